// Round 1
// baseline (240.123 us; speedup 1.0000x reference)
//
#include <hip/hip_runtime.h>

#define DD 4096
#define CC 4096
#define HH 8192

// ---------------- elementwise kernels ----------------

__global__ __launch_bounds__(256) void ew_concat(const float* __restrict__ h,
                                                 const float* __restrict__ c,
                                                 float* __restrict__ x0) {
    int i = blockIdx.x * 256 + threadIdx.x;
    x0[i] = (i < DD) ? h[i] : c[i - DD];
}

__global__ __launch_bounds__(256) void ew_tanh(const float* __restrict__ a0,
                                               const float* __restrict__ b1,
                                               float* __restrict__ s0,
                                               float* __restrict__ t0) {
    int i = blockIdx.x * 256 + threadIdx.x;
    float s = tanhf(a0[i] + b1[i]);
    s0[i] = s;
    t0[i] = 1.0f - s * s;
}

__global__ __launch_bounds__(256) void ew_addb_out(const float* __restrict__ Fr,
                                                   const float* __restrict__ b2,
                                                   float* __restrict__ Ff,
                                                   float* __restrict__ dout) {
    int i = blockIdx.x * 256 + threadIdx.x;
    float f = Fr[i] + b2[i];
    Ff[i] = f;
    dout[i] = f;
}

__global__ __launch_bounds__(256) void ew_mul(const float* __restrict__ t0,
                                              const float* __restrict__ a1,
                                              float* __restrict__ p1) {
    int i = blockIdx.x * 256 + threadIdx.x;
    p1[i] = t0[i] * a1[i];
}

__global__ __launch_bounds__(256) void ew_s2(const float* __restrict__ t0,
                                             const float* __restrict__ s0,
                                             const float* __restrict__ a1,
                                             const float* __restrict__ a2,
                                             float* __restrict__ s2) {
    int i = blockIdx.x * 256 + threadIdx.x;
    float a1v = a1[i];
    s2[i] = t0[i] * (a2[i] - s0[i] * a1v * a1v);
}

// ---------------- GEMV: out[n] += sum_k x[k] * W[k*N + n] ----------------
// W row-major K x N. Block: 256 threads, each thread 4 consecutive columns
// (float4 load => 16B/lane coalesced). Grid: (N/1024, K/KS). atomicAdd f32.

__global__ __launch_bounds__(256) void gemv_acc(const float* __restrict__ W,
                                                const float* __restrict__ x,
                                                float* __restrict__ out,
                                                int N, int KS) {
    const int ncol = blockIdx.x * 1024 + threadIdx.x * 4;
    const int k0 = blockIdx.y * KS;
    const float* Wp = W + (size_t)k0 * (size_t)N + ncol;
    const float* xp = x + k0;

    float ax = 0.f, ay = 0.f, az = 0.f, aw = 0.f;
#pragma unroll 4
    for (int k = 0; k < KS; ++k) {
        float xv = xp[k];
        float4 w = *reinterpret_cast<const float4*>(Wp + (size_t)k * (size_t)N);
        ax = fmaf(xv, w.x, ax);
        ay = fmaf(xv, w.y, ay);
        az = fmaf(xv, w.z, az);
        aw = fmaf(xv, w.w, aw);
    }
    float* op = out + ncol;
    atomicAdd(op + 0, ax);
    atomicAdd(op + 1, ay);
    atomicAdd(op + 2, az);
    atomicAdd(op + 3, aw);
}

// ---------------- reduce: d_out[DD] = mean(C2^2) ----------------

__global__ __launch_bounds__(256) void reduce_meansq(const float* __restrict__ C2v,
                                                     float* __restrict__ dout) {
    float s = 0.f;
    for (int i = threadIdx.x; i < DD; i += 256) {
        float v = C2v[i];
        s = fmaf(v, v, s);
    }
    for (int off = 32; off; off >>= 1) s += __shfl_down(s, off);
    __shared__ float ls[4];
    int wid = threadIdx.x >> 6;
    if ((threadIdx.x & 63) == 0) ls[wid] = s;
    __syncthreads();
    if (threadIdx.x == 0) {
        float tot = ls[0] + ls[1] + ls[2] + ls[3];
        dout[DD] = tot / (float)DD;
    }
}

// ---------------- launch ----------------

extern "C" void kernel_launch(void* const* d_in, const int* in_sizes, int n_in,
                              void* d_out, int out_size, void* d_ws, size_t ws_size,
                              hipStream_t stream) {
    const float* h  = (const float*)d_in[0];
    // d_in[1] = r (ignored), d_in[2] = t (ignored)
    const float* c  = (const float*)d_in[3];
    const float* W1 = (const float*)d_in[4];   // (DD+CC) x HH
    const float* b1 = (const float*)d_in[5];   // HH
    const float* W2 = (const float*)d_in[6];   // HH x DD
    const float* b2 = (const float*)d_in[7];   // DD

    float* out = (float*)d_out;                // [0..4095]=dydt, [4096]=mean(drdt^2)
    float* ws = (float*)d_ws;

    // accumulator region (zeroed each call), then scratch vectors
    float* a0 = ws + 0;       // 8192
    float* Fr = ws + 8192;    // 4096
    float* a1 = ws + 12288;   // 8192
    float* v  = ws + 20480;   // 4096
    float* a2 = ws + 24576;   // 8192
    float* C2 = ws + 32768;   // 4096
    float* x0 = ws + 36864;   // 8192
    float* s0 = ws + 45056;   // 8192
    float* t0 = ws + 53248;   // 8192
    float* Ff = ws + 61440;   // 4096
    float* p1 = ws + 65536;   // 8192
    float* s2 = ws + 73728;   // 8192

    hipMemsetAsync(ws, 0, 36864 * sizeof(float), stream);

    // x0 = concat(h, c)
    ew_concat<<<32, 256, 0, stream>>>(h, c, x0);
    // a0 = x0 @ W1   (K=8192, N=8192)
    gemv_acc<<<dim3(8, 64), 256, 0, stream>>>(W1, x0, a0, HH, 128);
    // s0 = tanh(a0 + b1), t0 = 1 - s0^2
    ew_tanh<<<32, 256, 0, stream>>>(a0, b1, s0, t0);
    // Fr = s0 @ W2   (K=8192, N=4096)
    gemv_acc<<<dim3(4, 128), 256, 0, stream>>>(W2, s0, Fr, DD, 64);
    // Ff = Fr + b2 -> out[0..4095]
    ew_addb_out<<<16, 256, 0, stream>>>(Fr, b2, Ff, out);
    // a1 = Ff @ W1[:DD]   (K=4096, N=8192)
    gemv_acc<<<dim3(8, 64), 256, 0, stream>>>(W1, Ff, a1, HH, 64);
    // p1 = t0 * a1
    ew_mul<<<32, 256, 0, stream>>>(t0, a1, p1);
    // v = p1 @ W2   (K=8192, N=4096)
    gemv_acc<<<dim3(4, 128), 256, 0, stream>>>(W2, p1, v, DD, 64);
    // a2 = v @ W1[:DD]   (K=4096, N=8192)
    gemv_acc<<<dim3(8, 64), 256, 0, stream>>>(W1, v, a2, HH, 64);
    // s2 = t0*a2 - s0*t0*a1^2
    ew_s2<<<32, 256, 0, stream>>>(t0, s0, a1, a2, s2);
    // C2 = s2 @ W2   (K=8192, N=4096)
    gemv_acc<<<dim3(4, 128), 256, 0, stream>>>(W2, s2, C2, DD, 64);
    // out[4096] = mean(C2^2)
    reduce_meansq<<<1, 256, 0, stream>>>(C2, out);
}

// Round 2
// 214.598 us; speedup vs baseline: 1.1189x; 1.1189x over previous
//
#include <hip/hip_runtime.h>

#define DD 4096
#define HH 8192

// Stage ids for the fused prologue (reduce prev partials + elementwise -> x in LDS)
enum Stage { S_X0 = 0, S_TANH, S_BIASOUT, S_PMUL, S_COPY, S_S2 };

// One split-K GEMV step:
//   prologue: x[k0:k0+KS) built in LDS (from h/c, or by reducing Pprev + elementwise)
//   main:     Pout[blockIdx.y][ncol..] = sum_{k in slice} x[k] * W[k][ncol..]
// W row-major K x NTOT. Grid: (NTOT/(256*CPT), K/KS). 256 threads.
template <int STAGE, int KS, int SPREV, int KPREV, int NTOT, int CPT>
__global__ __launch_bounds__(256) void gemv_stage(
    const float* __restrict__ W,
    const float* __restrict__ Pprev,
    float* __restrict__ Pout,
    const float* __restrict__ h, const float* __restrict__ c,
    const float* __restrict__ b1, const float* __restrict__ b2,
    float* __restrict__ s0g, float* __restrict__ t0g, float* __restrict__ a1g,
    float* __restrict__ outv)
{
    constexpr int GROUPS = 256 / KS;
    __shared__ float xs[KS];
    __shared__ float part[GROUPS][KS];

    const int tid = threadIdx.x;
    const int k0 = blockIdx.y * KS;

    if constexpr (STAGE == S_X0) {
        if (tid < KS) {
            int k = k0 + tid;
            xs[tid] = (k < DD) ? h[k] : c[k - DD];
        }
    } else {
        const int g = tid / KS;
        const int j = tid % KS;
        float acc = 0.f;
        for (int s = g; s < SPREV; s += GROUPS)
            acc += Pprev[(size_t)s * KPREV + k0 + j];
        part[g][j] = acc;
        __syncthreads();
        if (tid < KS) {
            const int k = k0 + tid;
            float tot = 0.f;
#pragma unroll
            for (int g2 = 0; g2 < GROUPS; ++g2) tot += part[g2][tid];
            float xv;
            if constexpr (STAGE == S_TANH) {
                float s = tanhf(tot + b1[k]);
                float t = 1.f - s * s;
                xv = s;
                if (blockIdx.x == 0) { s0g[k] = s; t0g[k] = t; }
            } else if constexpr (STAGE == S_BIASOUT) {
                xv = tot + b2[k];
                if (blockIdx.x == 0) outv[k] = xv;
            } else if constexpr (STAGE == S_PMUL) {
                xv = t0g[k] * tot;
                if (blockIdx.x == 0) a1g[k] = tot;
            } else if constexpr (STAGE == S_COPY) {
                xv = tot;
            } else { // S_S2
                float a1v = a1g[k];
                xv = t0g[k] * (tot - s0g[k] * a1v * a1v);
            }
            xs[tid] = xv;
        }
    }
    __syncthreads();

    if constexpr (CPT == 4) {
        const int ncol = blockIdx.x * 1024 + tid * 4;
        const float* Wp = W + (size_t)k0 * NTOT + ncol;
        float ax = 0.f, ay = 0.f, az = 0.f, aw = 0.f;
#pragma unroll 8
        for (int k = 0; k < KS; ++k) {
            float xv = xs[k];
            float4 w = *reinterpret_cast<const float4*>(Wp + (size_t)k * NTOT);
            ax = fmaf(xv, w.x, ax);
            ay = fmaf(xv, w.y, ay);
            az = fmaf(xv, w.z, az);
            aw = fmaf(xv, w.w, aw);
        }
        *reinterpret_cast<float4*>(Pout + (size_t)blockIdx.y * NTOT + ncol) =
            make_float4(ax, ay, az, aw);
    } else {
        const int ncol = blockIdx.x * 512 + tid * 2;
        const float* Wp = W + (size_t)k0 * NTOT + ncol;
        float ax = 0.f, ay = 0.f;
#pragma unroll 8
        for (int k = 0; k < KS; ++k) {
            float xv = xs[k];
            float2 w = *reinterpret_cast<const float2*>(Wp + (size_t)k * NTOT);
            ax = fmaf(xv, w.x, ax);
            ay = fmaf(xv, w.y, ay);
        }
        *reinterpret_cast<float2*>(Pout + (size_t)blockIdx.y * NTOT + ncol) =
            make_float2(ax, ay);
    }
}

// C2[n] = sum_s P6[s][n]
__global__ __launch_bounds__(256) void reduce_C2(const float* __restrict__ P6,
                                                 float* __restrict__ C2) {
    int n = blockIdx.x * 256 + threadIdx.x;
    float acc = 0.f;
#pragma unroll 8
    for (int s = 0; s < 128; ++s) acc += P6[(size_t)s * DD + n];
    C2[n] = acc;
}

// out[DD] = mean(C2^2)
__global__ __launch_bounds__(256) void reduce_meansq(const float* __restrict__ C2v,
                                                     float* __restrict__ dout) {
    float s = 0.f;
    for (int i = threadIdx.x; i < DD; i += 256) {
        float v = C2v[i];
        s = fmaf(v, v, s);
    }
    for (int off = 32; off; off >>= 1) s += __shfl_down(s, off);
    __shared__ float ls[4];
    int wid = threadIdx.x >> 6;
    if ((threadIdx.x & 63) == 0) ls[wid] = s;
    __syncthreads();
    if (threadIdx.x == 0) {
        dout[DD] = (ls[0] + ls[1] + ls[2] + ls[3]) / (float)DD;
    }
}

extern "C" void kernel_launch(void* const* d_in, const int* in_sizes, int n_in,
                              void* d_out, int out_size, void* d_ws, size_t ws_size,
                              hipStream_t stream) {
    const float* h  = (const float*)d_in[0];
    const float* c  = (const float*)d_in[3];
    const float* W1 = (const float*)d_in[4];   // (DD+CC) x HH row-major
    const float* b1 = (const float*)d_in[5];
    const float* W2 = (const float*)d_in[6];   // HH x DD row-major
    const float* b2 = (const float*)d_in[7];
    float* out = (float*)d_out;                // [0..4095]=dydt, [4096]=mean(drdt^2)
    float* ws = (float*)d_ws;

    // workspace layout (floats)
    float* P1 = ws;                 // 128 x 8192
    float* P2 = P1 + 1048576;       // 128 x 4096
    float* P3 = P2 + 524288;        // 128 x 8192
    float* P4 = P3 + 1048576;       // 128 x 4096
    float* P5 = P4 + 524288;        // 128 x 8192
    float* P6 = P5 + 1048576;       // 128 x 4096
    float* s0 = P6 + 524288;        // 8192
    float* t0 = s0 + 8192;          // 8192
    float* a1 = t0 + 8192;          // 8192
    float* C2 = a1 + 8192;          // 4096

    // G1: a0 partials = concat(h,c) @ W1          (K=8192, N=8192)
    gemv_stage<S_X0, 64, 1, 1, HH, 4><<<dim3(8, 128), 256, 0, stream>>>(
        W1, nullptr, P1, h, c, b1, b2, s0, t0, a1, out);
    // G2: s0 = tanh(a0+b1); Fr partials = s0 @ W2 (K=8192, N=4096)
    gemv_stage<S_TANH, 64, 128, HH, DD, 2><<<dim3(8, 128), 256, 0, stream>>>(
        W2, P1, P2, h, c, b1, b2, s0, t0, a1, out);
    // G3: Ff = Fr+b2 -> out; a1 partials = Ff @ W1_h (K=4096, N=8192)
    gemv_stage<S_BIASOUT, 32, 128, DD, HH, 4><<<dim3(8, 128), 256, 0, stream>>>(
        W1, P2, P3, h, c, b1, b2, s0, t0, a1, out);
    // G4: p1 = t0*a1; v partials = p1 @ W2        (K=8192, N=4096)
    gemv_stage<S_PMUL, 64, 128, HH, DD, 2><<<dim3(8, 128), 256, 0, stream>>>(
        W2, P3, P4, h, c, b1, b2, s0, t0, a1, out);
    // G5: v; a2 partials = v @ W1_h               (K=4096, N=8192)
    gemv_stage<S_COPY, 32, 128, DD, HH, 4><<<dim3(8, 128), 256, 0, stream>>>(
        W1, P4, P5, h, c, b1, b2, s0, t0, a1, out);
    // G6: s2 = t0*(a2 - s0*a1^2); C2 partials = s2 @ W2 (K=8192, N=4096)
    gemv_stage<S_S2, 64, 128, HH, DD, 2><<<dim3(8, 128), 256, 0, stream>>>(
        W2, P5, P6, h, c, b1, b2, s0, t0, a1, out);
    // C2 = reduce(P6)
    reduce_C2<<<16, 256, 0, stream>>>(P6, C2);
    // out[4096] = mean(C2^2)
    reduce_meansq<<<1, 256, 0, stream>>>(C2, out);
}